// Round 1
// baseline (10107.404 us; speedup 1.0000x reference)
//
#include <hip/hip_runtime.h>
#include <math.h>

#define USER_NUM 50000
#define ITEM_NUM 100000
#define NN (USER_NUM + ITEM_NUM)
#define D 64
#define TAU_INV 2.0f   // 1/0.5
#define LMBD 0.0001f

// ---------------- init: h_cur = concat(user,item); acc = same; h_next = 0
__global__ void init_kernel(const float* __restrict__ ue, const float* __restrict__ ie,
                            float* __restrict__ h, float* __restrict__ acc,
                            float* __restrict__ hn) {
    int i = blockIdx.x * 256 + threadIdx.x;
    if (i < NN * D) {
        float v = (i < USER_NUM * D) ? ue[i] : ie[i - USER_NUM * D];
        h[i] = v; acc[i] = v; hn[i] = 0.f;
    }
}

// ---------------- scatter: one wave per edge, lane = dim
__global__ void scatter_kernel(const float* __restrict__ h, const int* __restrict__ src,
                               const int* __restrict__ dst, const float* __restrict__ w,
                               float* __restrict__ hn, int E) {
    int gid = blockIdx.x * 256 + threadIdx.x;
    int e = gid >> 6;
    int lane = gid & 63;
    if (e >= E) return;
    int s = src[e];
    int d = dst[e];
    float v = h[(size_t)s * D + lane] * w[e];
    atomicAdd(&hn[(size_t)d * D + lane], v);
}

// ---------------- row l2-normalize (in place) + acc += ; zero the other buffer
__global__ void norm_acc_kernel(float* __restrict__ h, float* __restrict__ acc,
                                float* __restrict__ zbuf) {
    int gid = blockIdx.x * 256 + threadIdx.x;
    int row = gid >> 6;
    int lane = gid & 63;
    if (row >= NN) return;
    size_t idx = (size_t)row * D + lane;
    float x = h[idx];
    float s = x * x;
    #pragma unroll
    for (int o = 32; o; o >>= 1) s += __shfl_xor(s, o);
    float y = x / fmaxf(sqrtf(s), 1e-12f);
    h[idx] = y;
    acc[idx] += y;
    zbuf[idx] = 0.f;
}

// ---------------- row l2-normalize in place (no acc)
__global__ void norm_rows_kernel(float* __restrict__ h) {
    int gid = blockIdx.x * 256 + threadIdx.x;
    int row = gid >> 6;
    int lane = gid & 63;
    if (row >= NN) return;
    size_t idx = (size_t)row * D + lane;
    float x = h[idx];
    float s = x * x;
    #pragma unroll
    for (int o = 32; o; o >>= 1) s += __shfl_xor(s, o);
    h[idx] = x / fmaxf(sqrtf(s), 1e-12f);
}

// ---------------- BPR: wave per sample
__global__ void bpr_kernel(const float* __restrict__ acc, const int* __restrict__ uid,
                           const int* __restrict__ iid, const int* __restrict__ nid,
                           float* __restrict__ scal, int B) {
    int gid = blockIdx.x * 256 + threadIdx.x;
    int r = gid >> 6;
    int lane = gid & 63;
    if (r >= B) return;
    const float inv = 1.0f / 5.0f;  // MAIN_LAYERS+1
    float ue = acc[(size_t)uid[r] * D + lane] * inv;
    float pe = acc[(size_t)(USER_NUM + iid[r]) * D + lane] * inv;
    float ne = acc[(size_t)(USER_NUM + nid[r]) * D + lane] * inv;
    float pos = ue * pe, neg = ue * ne, reg = ue * ue + pe * pe + ne * ne;
    #pragma unroll
    for (int o = 32; o; o >>= 1) {
        pos += __shfl_xor(pos, o);
        neg += __shfl_xor(neg, o);
        reg += __shfl_xor(reg, o);
    }
    if (lane == 0) {
        float x = pos - neg;
        // log_sigmoid(x), numerically stable
        float ls = (x >= 0.f) ? (-log1pf(expf(-x))) : (x - log1pf(expf(x)));
        atomicAdd(&scal[0], -ls);
        atomicAdd(&scal[1], reg * 0.5f);
    }
}

// ---------------- extract sampled rows from acc, l2-normalize -> ue1 / ie1
__global__ void extract_norm_kernel(const float* __restrict__ acc, const int* __restrict__ uid,
                                    const int* __restrict__ iid, float* __restrict__ ue1,
                                    float* __restrict__ ie1, int B) {
    int gid = blockIdx.x * 256 + threadIdx.x;
    int t = gid >> 6;
    int lane = gid & 63;
    if (t >= 2 * B) return;
    bool user = (t < B);
    int r = user ? t : (t - B);
    size_t srow = user ? (size_t)uid[r] * D : (size_t)(USER_NUM + iid[r]) * D;
    float x = acc[srow + lane];
    float s = x * x;
    #pragma unroll
    for (int o = 32; o; o >>= 1) s += __shfl_xor(s, o);
    float y = x / fmaxf(sqrtf(s), 1e-12f);
    (user ? ue1 : ie1)[(size_t)r * D + lane] = y;
}

// ---------------- big SSL: rowsum[r] += sum_j exp(dot(A[r], Bm[j]) / tau)
// grid: (ceil(M/256), B/64); block 256. A tile 64x64 in LDS; thread owns col j.
__global__ __launch_bounds__(256) void ssl_big_kernel(const float* __restrict__ A,
                                                      const float* __restrict__ Bm,
                                                      float* __restrict__ rowsum,
                                                      int M) {
    __shared__ float As[64][68];  // stride 68 floats: rows stay 16B-aligned
    int rowbase = blockIdx.y * 64;
    int tid = threadIdx.x;
    // stage A tile: 1024 float4
    {
        const float4* Af = (const float4*)(A + (size_t)rowbase * D);
        for (int idx = tid; idx < 1024; idx += 256) {
            float4 v = Af[idx];
            int rr = idx >> 4;
            int cc = (idx & 15) << 2;
            *(float4*)&As[rr][cc] = v;
        }
    }
    __syncthreads();
    int j = blockIdx.x * 256 + tid;
    bool act = (j < M);
    float b[64];
    if (act) {
        const float4* Bf = (const float4*)(Bm + (size_t)j * D);
        #pragma unroll
        for (int q = 0; q < 16; q++) {
            float4 v = Bf[q];
            b[4*q] = v.x; b[4*q+1] = v.y; b[4*q+2] = v.z; b[4*q+3] = v.w;
        }
    } else {
        #pragma unroll
        for (int q = 0; q < 64; q++) b[q] = 0.f;
    }
    int lane = tid & 63;
    #pragma unroll 4
    for (int r = 0; r < 64; r++) {
        float dot = 0.f;
        const float4* ar = (const float4*)(&As[r][0]);
        #pragma unroll
        for (int q = 0; q < 16; q++) {
            float4 a4 = ar[q];
            dot += a4.x * b[4*q] + a4.y * b[4*q+1] + a4.z * b[4*q+2] + a4.w * b[4*q+3];
        }
        float e = act ? expf(dot * TAU_INV) : 0.f;
        #pragma unroll
        for (int o = 32; o; o >>= 1) e += __shfl_xor(e, o);
        if (lane == 0) atomicAdd(&rowsum[rowbase + r], e);
    }
}

// ---------------- SSL finalize: sum_r [ log(rowsum[r]) - dot(x1[r], A2[id_r])/tau ]
__global__ void ssl_fin_kernel(const float* __restrict__ ue1, const float* __restrict__ ie1,
                               const float* __restrict__ A2, const int* __restrict__ uid,
                               const int* __restrict__ iid, const float* __restrict__ rsU,
                               const float* __restrict__ rsI, float* __restrict__ scal, int B) {
    int gid = blockIdx.x * 256 + threadIdx.x;
    int t = gid >> 6;
    int lane = gid & 63;
    if (t >= 2 * B) return;
    bool user = (t < B);
    int r = user ? t : (t - B);
    const float* a = (user ? ue1 : ie1) + (size_t)r * D;
    size_t brow = user ? (size_t)uid[r] * D : (size_t)(USER_NUM + iid[r]) * D;
    float p = a[lane] * A2[brow + lane];
    #pragma unroll
    for (int o = 32; o; o >>= 1) p += __shfl_xor(p, o);
    if (lane == 0) {
        float contrib = logf((user ? rsU : rsI)[r]) - p * TAU_INV;
        atomicAdd(&scal[user ? 2 : 3], contrib);
    }
}

// ---------------- final scalar
__global__ void final_kernel(const float* __restrict__ scal, float* __restrict__ out, int B) {
    if (threadIdx.x == 0 && blockIdx.x == 0) {
        float invB = 1.0f / (float)B;
        float bpr_loss = scal[0] * invB + LMBD * scal[1] * invB;
        float ssl_loss = (scal[2] + scal[3]) * 0.1f;
        out[0] = bpr_loss + ssl_loss;
    }
}

extern "C" void kernel_launch(void* const* d_in, const int* in_sizes, int n_in,
                              void* d_out, int out_size, void* d_ws, size_t ws_size,
                              hipStream_t stream) {
    const float* user_emb = (const float*)d_in[0];
    const float* item_emb = (const float*)d_in[1];
    const int*   src  = (const int*)d_in[2];
    const int*   dst  = (const int*)d_in[3];
    const float* w    = (const float*)d_in[4];
    const int*   src1 = (const int*)d_in[5];
    const int*   dst1 = (const int*)d_in[6];
    const float* w1   = (const float*)d_in[7];
    const int*   src2 = (const int*)d_in[8];
    const int*   dst2 = (const int*)d_in[9];
    const float* w2   = (const float*)d_in[10];
    const int* user_id = (const int*)d_in[11];
    const int* item_id = (const int*)d_in[12];
    const int* neg_id  = (const int*)d_in[13];
    int E0 = in_sizes[2];
    int E1 = in_sizes[5];
    int E2 = in_sizes[8];
    int B  = in_sizes[11];

    size_t nd = (size_t)NN * D;
    float* hA  = (float*)d_ws;
    float* hB  = hA + nd;
    float* acc = hB + nd;
    float* ue1 = acc + nd;
    float* ie1 = ue1 + (size_t)B * D;
    float* rsU = ie1 + (size_t)B * D;
    float* rsI = rsU + B;
    float* scal = rsI + B;

    // zero rowsums + scalar accumulators (one small memset)
    hipMemsetAsync(rsU, 0, (size_t)(2 * B + 8) * sizeof(float), stream);

    int gridElem = (NN * D + 255) / 256;

    auto propagate = [&](const int* s_, const int* d_, const float* w_, int E_, int layers) {
        init_kernel<<<gridElem, 256, 0, stream>>>(user_emb, item_emb, hA, acc, hB);
        float* cur = hA;
        float* nxt = hB;
        for (int l = 0; l < layers; l++) {
            int gs = (int)(((size_t)E_ * 64 + 255) / 256);
            scatter_kernel<<<gs, 256, 0, stream>>>(cur, s_, d_, w_, nxt, E_);
            norm_acc_kernel<<<gridElem, 256, 0, stream>>>(nxt, acc, cur);
            float* t = cur; cur = nxt; nxt = t;
        }
    };

    // main graph: 4 layers -> BPR
    propagate(src, dst, w, E0, 4);
    bpr_kernel<<<(B * 64) / 256, 256, 0, stream>>>(acc, user_id, item_id, neg_id, scal, B);

    // ssl graph 1: 3 layers -> ue1/ie1 (normalized sampled rows)
    propagate(src1, dst1, w1, E1, 3);
    extract_norm_kernel<<<(2 * B * 64) / 256, 256, 0, stream>>>(acc, user_id, item_id, ue1, ie1, B);

    // ssl graph 2: 3 layers -> normalize all rows in place (au2 | ai2)
    propagate(src2, dst2, w2, E2, 3);
    norm_rows_kernel<<<gridElem, 256, 0, stream>>>(acc);

    // big SSL terms
    {
        dim3 gu((USER_NUM + 255) / 256, B / 64);
        ssl_big_kernel<<<gu, 256, 0, stream>>>(ue1, acc, rsU, USER_NUM);
        dim3 gi((ITEM_NUM + 255) / 256, B / 64);
        ssl_big_kernel<<<gi, 256, 0, stream>>>(ie1, acc + (size_t)USER_NUM * D, rsI, ITEM_NUM);
    }

    ssl_fin_kernel<<<(2 * B * 64) / 256, 256, 0, stream>>>(ue1, ie1, acc, user_id, item_id,
                                                           rsU, rsI, scal, B);
    final_kernel<<<1, 64, 0, stream>>>(scal, (float*)d_out, B);
}

// Round 2
// 6704.213 us; speedup vs baseline: 1.5076x; 1.5076x over previous
//
#include <hip/hip_runtime.h>
#include <math.h>

#define USER_NUM 50000
#define ITEM_NUM 100000
#define NN (USER_NUM + ITEM_NUM)
#define D 64
#define TAU_INV 2.0f   // 1/0.5
#define LMBD 0.0001f

typedef __bf16 bf16x8 __attribute__((ext_vector_type(8)));
typedef float  f32x4  __attribute__((ext_vector_type(4)));

static __device__ __forceinline__ unsigned short f2bf(float x) {
    union { float f; unsigned u; } v; v.f = x;
    unsigned r = v.u + 0x7FFFu + ((v.u >> 16) & 1u);   // RNE
    return (unsigned short)(r >> 16);
}

// ---------------- init: h_cur = concat(user,item); acc = same; h_next = 0
__global__ void init_kernel(const float* __restrict__ ue, const float* __restrict__ ie,
                            float* __restrict__ h, float* __restrict__ acc,
                            float* __restrict__ hn) {
    int i = blockIdx.x * 256 + threadIdx.x;
    if (i < NN * D) {
        float v = (i < USER_NUM * D) ? ue[i] : ie[i - USER_NUM * D];
        h[i] = v; acc[i] = v; hn[i] = 0.f;
    }
}

// ---------------- scatter: one wave per edge, lane = dim
__global__ void scatter_kernel(const float* __restrict__ h, const int* __restrict__ src,
                               const int* __restrict__ dst, const float* __restrict__ w,
                               float* __restrict__ hn, int E) {
    int gid = blockIdx.x * 256 + threadIdx.x;
    int e = gid >> 6;
    int lane = gid & 63;
    if (e >= E) return;
    int s = src[e];
    int d = dst[e];
    float v = h[(size_t)s * D + lane] * w[e];
    atomicAdd(&hn[(size_t)d * D + lane], v);
}

// ---------------- row l2-normalize (in place) + acc += ; zero the other buffer
__global__ void norm_acc_kernel(float* __restrict__ h, float* __restrict__ acc,
                                float* __restrict__ zbuf) {
    int gid = blockIdx.x * 256 + threadIdx.x;
    int row = gid >> 6;
    int lane = gid & 63;
    if (row >= NN) return;
    size_t idx = (size_t)row * D + lane;
    float x = h[idx];
    float s = x * x;
    #pragma unroll
    for (int o = 32; o; o >>= 1) s += __shfl_xor(s, o);
    float y = x / fmaxf(sqrtf(s), 1e-12f);
    h[idx] = y;
    acc[idx] += y;
    zbuf[idx] = 0.f;
}

// ---------------- row l2-normalize in place + write bf16 copy
__global__ void norm_rows_bf_kernel(float* __restrict__ h, unsigned short* __restrict__ hb) {
    int gid = blockIdx.x * 256 + threadIdx.x;
    int row = gid >> 6;
    int lane = gid & 63;
    if (row >= NN) return;
    size_t idx = (size_t)row * D + lane;
    float x = h[idx];
    float s = x * x;
    #pragma unroll
    for (int o = 32; o; o >>= 1) s += __shfl_xor(s, o);
    float y = x / fmaxf(sqrtf(s), 1e-12f);
    h[idx] = y;
    hb[idx] = f2bf(y);
}

// ---------------- BPR: wave per sample
__global__ void bpr_kernel(const float* __restrict__ acc, const int* __restrict__ uid,
                           const int* __restrict__ iid, const int* __restrict__ nid,
                           float* __restrict__ scal, int B) {
    int gid = blockIdx.x * 256 + threadIdx.x;
    int r = gid >> 6;
    int lane = gid & 63;
    if (r >= B) return;
    const float inv = 1.0f / 5.0f;  // MAIN_LAYERS+1
    float ue = acc[(size_t)uid[r] * D + lane] * inv;
    float pe = acc[(size_t)(USER_NUM + iid[r]) * D + lane] * inv;
    float ne = acc[(size_t)(USER_NUM + nid[r]) * D + lane] * inv;
    float pos = ue * pe, neg = ue * ne, reg = ue * ue + pe * pe + ne * ne;
    #pragma unroll
    for (int o = 32; o; o >>= 1) {
        pos += __shfl_xor(pos, o);
        neg += __shfl_xor(neg, o);
        reg += __shfl_xor(reg, o);
    }
    if (lane == 0) {
        float x = pos - neg;
        float ls = (x >= 0.f) ? (-log1pf(expf(-x))) : (x - log1pf(expf(x)));
        atomicAdd(&scal[0], -ls);
        atomicAdd(&scal[1], reg * 0.5f);
    }
}

// ---------------- extract sampled rows from acc, l2-normalize -> bf16 ue1b / ie1b
__global__ void extract_norm_kernel(const float* __restrict__ acc, const int* __restrict__ uid,
                                    const int* __restrict__ iid, unsigned short* __restrict__ ue1b,
                                    unsigned short* __restrict__ ie1b, int B) {
    int gid = blockIdx.x * 256 + threadIdx.x;
    int t = gid >> 6;
    int lane = gid & 63;
    if (t >= 2 * B) return;
    bool user = (t < B);
    int r = user ? t : (t - B);
    size_t srow = user ? (size_t)uid[r] * D : (size_t)(USER_NUM + iid[r]) * D;
    float x = acc[srow + lane];
    float s = x * x;
    #pragma unroll
    for (int o = 32; o; o >>= 1) s += __shfl_xor(s, o);
    float y = x / fmaxf(sqrtf(s), 1e-12f);
    (user ? ue1b : ie1b)[(size_t)r * D + lane] = f2bf(y);
}

// ---------------- big SSL via MFMA: rowsum[r] += sum_j exp(2*dot(A[r], B[j]))
// A: 4096x64 bf16; B: Mx64 bf16. Block 256 = 4 waves; wave owns 32 cols;
// loop over 64 row-groups of 64 rows. No LDS.
__global__ __launch_bounds__(256) void ssl_mfma_kernel(const unsigned short* __restrict__ Ab,
                                                       const unsigned short* __restrict__ Bb,
                                                       float* __restrict__ rowsum, int M) {
    int wave = threadIdx.x >> 6;
    int lane = threadIdx.x & 63;
    int l15 = lane & 15;
    int lg  = lane >> 4;
    int colbase = blockIdx.x * 128 + wave * 32;

    // load B fragments once: bfr[cf][k8]; col = colbase + cf*16 + l15
    bf16x8 bfr[2][2];
    bool valid[2];
    #pragma unroll
    for (int cf = 0; cf < 2; cf++) {
        int col = colbase + cf * 16 + l15;
        valid[cf] = (col < M);
        int crow = valid[cf] ? col : (M - 1);
        const unsigned short* bp = Bb + (size_t)crow * D + lg * 8;
        bfr[cf][0] = *(const bf16x8*)(bp);
        bfr[cf][1] = *(const bf16x8*)(bp + 32);
    }

    for (int rg = 0; rg < 64; rg++) {
        const unsigned short* ab = Ab + ((size_t)(rg * 64 + l15)) * D + lg * 8;
        f32x4 acc[4][2];
        #pragma unroll
        for (int i = 0; i < 4; i++)
            #pragma unroll
            for (int cf = 0; cf < 2; cf++)
                acc[i][cf] = (f32x4){0.f, 0.f, 0.f, 0.f};

        #pragma unroll
        for (int i = 0; i < 4; i++) {
            bf16x8 a0 = *(const bf16x8*)(ab + (size_t)i * 16 * D);
            bf16x8 a1 = *(const bf16x8*)(ab + (size_t)i * 16 * D + 32);
            #pragma unroll
            for (int cf = 0; cf < 2; cf++) {
                acc[i][cf] = __builtin_amdgcn_mfma_f32_16x16x32_bf16(a0, bfr[cf][0], acc[i][cf], 0, 0, 0);
                acc[i][cf] = __builtin_amdgcn_mfma_f32_16x16x32_bf16(a1, bfr[cf][1], acc[i][cf], 0, 0, 0);
            }
        }

        // exp + reduce over cols (16-lane groups) + atomic per row
        #pragma unroll
        for (int i = 0; i < 4; i++) {
            #pragma unroll
            for (int r = 0; r < 4; r++) {
                float e0 = valid[0] ? __expf(TAU_INV * acc[i][0][r]) : 0.f;
                float e1 = valid[1] ? __expf(TAU_INV * acc[i][1][r]) : 0.f;
                float s = e0 + e1;
                s += __shfl_xor(s, 1);
                s += __shfl_xor(s, 2);
                s += __shfl_xor(s, 4);
                s += __shfl_xor(s, 8);
                if (l15 == 0) atomicAdd(&rowsum[rg * 64 + i * 16 + lg * 4 + r], s);
            }
        }
    }
}

// ---------------- SSL finalize: sum_r [ log(rowsum[r]) - dot(x1[r], A2[id_r])/tau ]
__global__ void ssl_fin_kernel(const unsigned short* __restrict__ ue1b,
                               const unsigned short* __restrict__ ie1b,
                               const float* __restrict__ A2, const int* __restrict__ uid,
                               const int* __restrict__ iid, const float* __restrict__ rsU,
                               const float* __restrict__ rsI, float* __restrict__ scal, int B) {
    int gid = blockIdx.x * 256 + threadIdx.x;
    int t = gid >> 6;
    int lane = gid & 63;
    if (t >= 2 * B) return;
    bool user = (t < B);
    int r = user ? t : (t - B);
    const unsigned short* a = (user ? ue1b : ie1b) + (size_t)r * D;
    size_t brow = user ? (size_t)uid[r] * D : (size_t)(USER_NUM + iid[r]) * D;
    union { unsigned u; float f; } cv; cv.u = ((unsigned)a[lane]) << 16;
    float p = cv.f * A2[brow + lane];
    #pragma unroll
    for (int o = 32; o; o >>= 1) p += __shfl_xor(p, o);
    if (lane == 0) {
        float contrib = logf((user ? rsU : rsI)[r]) - p * TAU_INV;
        atomicAdd(&scal[user ? 2 : 3], contrib);
    }
}

// ---------------- final scalar
__global__ void final_kernel(const float* __restrict__ scal, float* __restrict__ out, int B) {
    if (threadIdx.x == 0 && blockIdx.x == 0) {
        float invB = 1.0f / (float)B;
        float bpr_loss = scal[0] * invB + LMBD * scal[1] * invB;
        float ssl_loss = (scal[2] + scal[3]) * 0.1f;
        out[0] = bpr_loss + ssl_loss;
    }
}

extern "C" void kernel_launch(void* const* d_in, const int* in_sizes, int n_in,
                              void* d_out, int out_size, void* d_ws, size_t ws_size,
                              hipStream_t stream) {
    const float* user_emb = (const float*)d_in[0];
    const float* item_emb = (const float*)d_in[1];
    const int*   src  = (const int*)d_in[2];
    const int*   dst  = (const int*)d_in[3];
    const float* w    = (const float*)d_in[4];
    const int*   src1 = (const int*)d_in[5];
    const int*   dst1 = (const int*)d_in[6];
    const float* w1   = (const float*)d_in[7];
    const int*   src2 = (const int*)d_in[8];
    const int*   dst2 = (const int*)d_in[9];
    const float* w2   = (const float*)d_in[10];
    const int* user_id = (const int*)d_in[11];
    const int* item_id = (const int*)d_in[12];
    const int* neg_id  = (const int*)d_in[13];
    int E0 = in_sizes[2];
    int E1 = in_sizes[5];
    int E2 = in_sizes[8];
    int B  = in_sizes[11];

    size_t nd = (size_t)NN * D;
    float* hA  = (float*)d_ws;
    float* hB  = hA + nd;
    float* acc = hB + nd;
    float* ue1 = acc + nd;                      // region reused as bf16 buffers
    float* ie1 = ue1 + (size_t)B * D;
    float* rsU = ie1 + (size_t)B * D;
    float* rsI = rsU + B;
    float* scal = rsI + B;
    unsigned short* ue1b = (unsigned short*)ue1;
    unsigned short* ie1b = (unsigned short*)ie1;
    unsigned short* bbuf = (unsigned short*)hA;  // free after last propagation

    // zero rowsums + scalar accumulators
    hipMemsetAsync(rsU, 0, (size_t)(2 * B + 8) * sizeof(float), stream);

    int gridElem = (NN * D + 255) / 256;

    auto propagate = [&](const int* s_, const int* d_, const float* w_, int E_, int layers) {
        init_kernel<<<gridElem, 256, 0, stream>>>(user_emb, item_emb, hA, acc, hB);
        float* cur = hA;
        float* nxt = hB;
        for (int l = 0; l < layers; l++) {
            int gs = (int)(((size_t)E_ * 64 + 255) / 256);
            scatter_kernel<<<gs, 256, 0, stream>>>(cur, s_, d_, w_, nxt, E_);
            norm_acc_kernel<<<gridElem, 256, 0, stream>>>(nxt, acc, cur);
            float* t = cur; cur = nxt; nxt = t;
        }
    };

    // main graph: 4 layers -> BPR
    propagate(src, dst, w, E0, 4);
    bpr_kernel<<<(B * 64) / 256, 256, 0, stream>>>(acc, user_id, item_id, neg_id, scal, B);

    // ssl graph 1: 3 layers -> bf16 normalized sampled rows
    propagate(src1, dst1, w1, E1, 3);
    extract_norm_kernel<<<(2 * B * 64) / 256, 256, 0, stream>>>(acc, user_id, item_id, ue1b, ie1b, B);

    // ssl graph 2: 3 layers -> normalize all rows in place + bf16 copy
    propagate(src2, dst2, w2, E2, 3);
    norm_rows_bf_kernel<<<gridElem, 256, 0, stream>>>(acc, bbuf);

    // big SSL terms via MFMA
    {
        int gu = (USER_NUM + 127) / 128;
        ssl_mfma_kernel<<<gu, 256, 0, stream>>>(ue1b, bbuf, rsU, USER_NUM);
        int gi = (ITEM_NUM + 127) / 128;
        ssl_mfma_kernel<<<gi, 256, 0, stream>>>(ie1b, bbuf + (size_t)USER_NUM * D, rsI, ITEM_NUM);
    }

    ssl_fin_kernel<<<(2 * B * 64) / 256, 256, 0, stream>>>(ue1b, ie1b, acc, user_id, item_id,
                                                           rsU, rsI, scal, B);
    final_kernel<<<1, 64, 0, stream>>>(scal, (float*)d_out, B);
}

// Round 4
// 5192.068 us; speedup vs baseline: 1.9467x; 1.2912x over previous
//
#include <hip/hip_runtime.h>
#include <math.h>

#define USER_NUM 50000
#define ITEM_NUM 100000
#define NN (USER_NUM + ITEM_NUM)
#define D 64
#define TAU_INV 2.0f   // 1/0.5
#define LMBD 0.0001f
#define NCITER 16      // col-iterations per block: 128*16 = 2048 cols/block

typedef __bf16 bf16x8 __attribute__((ext_vector_type(8)));
typedef float  f32x4  __attribute__((ext_vector_type(4)));

static __device__ __forceinline__ unsigned short f2bf(float x) {
    union { float f; unsigned u; } v; v.f = x;
    unsigned r = v.u + 0x7FFFu + ((v.u >> 16) & 1u);   // RNE
    return (unsigned short)(r >> 16);
}

// ---------------- init: h_cur = concat(user,item); acc = same; h_next = 0
__global__ void init_kernel(const float* __restrict__ ue, const float* __restrict__ ie,
                            float* __restrict__ h, float* __restrict__ acc,
                            float* __restrict__ hn) {
    int i = blockIdx.x * 256 + threadIdx.x;
    if (i < NN * D) {
        float v = (i < USER_NUM * D) ? ue[i] : ie[i - USER_NUM * D];
        h[i] = v; acc[i] = v; hn[i] = 0.f;
    }
}

// ---------------- scatter: one wave per edge, lane = dim
__global__ void scatter_kernel(const float* __restrict__ h, const int* __restrict__ src,
                               const int* __restrict__ dst, const float* __restrict__ w,
                               float* __restrict__ hn, int E) {
    int gid = blockIdx.x * 256 + threadIdx.x;
    int e = gid >> 6;
    int lane = gid & 63;
    if (e >= E) return;
    int s = src[e];
    int d = dst[e];
    float v = h[(size_t)s * D + lane] * w[e];
    atomicAdd(&hn[(size_t)d * D + lane], v);
}

// ---------------- row l2-normalize (in place) + acc += ; zero the other buffer
__global__ void norm_acc_kernel(float* __restrict__ h, float* __restrict__ acc,
                                float* __restrict__ zbuf) {
    int gid = blockIdx.x * 256 + threadIdx.x;
    int row = gid >> 6;
    int lane = gid & 63;
    if (row >= NN) return;
    size_t idx = (size_t)row * D + lane;
    float x = h[idx];
    float s = x * x;
    #pragma unroll
    for (int o = 32; o; o >>= 1) s += __shfl_xor(s, o);
    float y = x / fmaxf(sqrtf(s), 1e-12f);
    h[idx] = y;
    acc[idx] += y;
    zbuf[idx] = 0.f;
}

// ---------------- row l2-normalize in place + write bf16 copy
__global__ void norm_rows_bf_kernel(float* __restrict__ h, unsigned short* __restrict__ hb) {
    int gid = blockIdx.x * 256 + threadIdx.x;
    int row = gid >> 6;
    int lane = gid & 63;
    if (row >= NN) return;
    size_t idx = (size_t)row * D + lane;
    float x = h[idx];
    float s = x * x;
    #pragma unroll
    for (int o = 32; o; o >>= 1) s += __shfl_xor(s, o);
    float y = x / fmaxf(sqrtf(s), 1e-12f);
    h[idx] = y;
    hb[idx] = f2bf(y);
}

// ---------------- BPR: wave per sample
__global__ void bpr_kernel(const float* __restrict__ acc, const int* __restrict__ uid,
                           const int* __restrict__ iid, const int* __restrict__ nid,
                           float* __restrict__ scal, int B) {
    int gid = blockIdx.x * 256 + threadIdx.x;
    int r = gid >> 6;
    int lane = gid & 63;
    if (r >= B) return;
    const float inv = 1.0f / 5.0f;  // MAIN_LAYERS+1
    float ue = acc[(size_t)uid[r] * D + lane] * inv;
    float pe = acc[(size_t)(USER_NUM + iid[r]) * D + lane] * inv;
    float ne = acc[(size_t)(USER_NUM + nid[r]) * D + lane] * inv;
    float pos = ue * pe, neg = ue * ne, reg = ue * ue + pe * pe + ne * ne;
    #pragma unroll
    for (int o = 32; o; o >>= 1) {
        pos += __shfl_xor(pos, o);
        neg += __shfl_xor(neg, o);
        reg += __shfl_xor(reg, o);
    }
    if (lane == 0) {
        float x = pos - neg;
        float ls = (x >= 0.f) ? (-log1pf(expf(-x))) : (x - log1pf(expf(x)));
        atomicAdd(&scal[0], -ls);
        atomicAdd(&scal[1], reg * 0.5f);
    }
}

// ---------------- extract sampled rows from acc, l2-normalize -> bf16 ue1b / ie1b
__global__ void extract_norm_kernel(const float* __restrict__ acc, const int* __restrict__ uid,
                                    const int* __restrict__ iid, unsigned short* __restrict__ ue1b,
                                    unsigned short* __restrict__ ie1b, int B) {
    int gid = blockIdx.x * 256 + threadIdx.x;
    int t = gid >> 6;
    int lane = gid & 63;
    if (t >= 2 * B) return;
    bool user = (t < B);
    int r = user ? t : (t - B);
    size_t srow = user ? (size_t)uid[r] * D : (size_t)(USER_NUM + iid[r]) * D;
    float x = acc[srow + lane];
    float s = x * x;
    #pragma unroll
    for (int o = 32; o; o >>= 1) s += __shfl_xor(s, o);
    float y = x / fmaxf(sqrtf(s), 1e-12f);
    (user ? ue1b : ie1b)[(size_t)r * D + lane] = f2bf(y);
}

// ---------------- big SSL via MFMA: rowsum[r] += sum_j exp(2*dot(A[r], B[j]))
// grid: (colChunks, 64 rowgroups); block 256 = 4 waves.
// Block owns rows [rg*64, rg*64+64) x cols [chunk*2048, +2048).
// exp sums accumulate in registers; one shuffle-reduce + 64 atomics per wave at end.
__global__ __launch_bounds__(256) void ssl_mfma_kernel(const unsigned short* __restrict__ Ab,
                                                       const unsigned short* __restrict__ Bb,
                                                       float* __restrict__ rowsum, int M) {
    int wave = threadIdx.x >> 6;
    int lane = threadIdx.x & 63;
    int l15 = lane & 15;
    int lg  = lane >> 4;
    int rgbase = blockIdx.y * 64;
    int chunkbase = blockIdx.x * (128 * NCITER);

    // load A fragments for this rowgroup:
    // afr[i]: row = rgbase + i*16 + l15, k = lg*8 .. +8 (and +32 for second frag)
    bf16x8 afr[4][2];
    {
        const unsigned short* ab = Ab + (size_t)(rgbase + l15) * D + lg * 8;
        #pragma unroll
        for (int i = 0; i < 4; i++) {
            afr[i][0] = *(const bf16x8*)(ab + (size_t)i * 16 * D);
            afr[i][1] = *(const bf16x8*)(ab + (size_t)i * 16 * D + 32);
        }
    }

    float rowacc[4][4];
    #pragma unroll
    for (int i = 0; i < 4; i++)
        #pragma unroll
        for (int r = 0; r < 4; r++) rowacc[i][r] = 0.f;

    for (int it = 0; it < NCITER; it++) {
        int cb = chunkbase + it * 128 + wave * 32;
        bf16x8 bfr[2][2];
        bool val[2];
        #pragma unroll
        for (int cf = 0; cf < 2; cf++) {
            int col = cb + cf * 16 + l15;
            val[cf] = (col < M);
            int cc = val[cf] ? col : (M - 1);
            const unsigned short* bp = Bb + (size_t)cc * D + lg * 8;
            bfr[cf][0] = *(const bf16x8*)(bp);
            bfr[cf][1] = *(const bf16x8*)(bp + 32);
        }

        f32x4 acc[4][2];
        #pragma unroll
        for (int i = 0; i < 4; i++)
            #pragma unroll
            for (int cf = 0; cf < 2; cf++)
                acc[i][cf] = (f32x4){0.f, 0.f, 0.f, 0.f};

        #pragma unroll
        for (int i = 0; i < 4; i++) {
            #pragma unroll
            for (int cf = 0; cf < 2; cf++) {
                acc[i][cf] = __builtin_amdgcn_mfma_f32_16x16x32_bf16(afr[i][0], bfr[cf][0], acc[i][cf], 0, 0, 0);
                acc[i][cf] = __builtin_amdgcn_mfma_f32_16x16x32_bf16(afr[i][1], bfr[cf][1], acc[i][cf], 0, 0, 0);
            }
        }

        #pragma unroll
        for (int i = 0; i < 4; i++) {
            #pragma unroll
            for (int r = 0; r < 4; r++) {
                float e0 = val[0] ? __expf(TAU_INV * acc[i][0][r]) : 0.f;
                float e1 = val[1] ? __expf(TAU_INV * acc[i][1][r]) : 0.f;
                rowacc[i][r] += e0 + e1;
            }
        }
    }

    // reduce each rowacc over the 16 col-lanes; one atomic per (row) per wave
    #pragma unroll
    for (int i = 0; i < 4; i++) {
        #pragma unroll
        for (int r = 0; r < 4; r++) {
            float s = rowacc[i][r];
            s += __shfl_xor(s, 1);
            s += __shfl_xor(s, 2);
            s += __shfl_xor(s, 4);
            s += __shfl_xor(s, 8);
            if (l15 == 0) atomicAdd(&rowsum[rgbase + i * 16 + lg * 4 + r], s);
        }
    }
}

// ---------------- SSL finalize: sum_r [ log(rowsum[r]) - dot(x1[r], A2[id_r])/tau ]
__global__ void ssl_fin_kernel(const unsigned short* __restrict__ ue1b,
                               const unsigned short* __restrict__ ie1b,
                               const float* __restrict__ A2, const int* __restrict__ uid,
                               const int* __restrict__ iid, const float* __restrict__ rsU,
                               const float* __restrict__ rsI, float* __restrict__ scal, int B) {
    int gid = blockIdx.x * 256 + threadIdx.x;
    int t = gid >> 6;
    int lane = gid & 63;
    if (t >= 2 * B) return;
    bool user = (t < B);
    int r = user ? t : (t - B);
    const unsigned short* a = (user ? ue1b : ie1b) + (size_t)r * D;
    size_t brow = user ? (size_t)uid[r] * D : (size_t)(USER_NUM + iid[r]) * D;
    union { unsigned u; float f; } cv; cv.u = ((unsigned)a[lane]) << 16;
    float p = cv.f * A2[brow + lane];
    #pragma unroll
    for (int o = 32; o; o >>= 1) p += __shfl_xor(p, o);
    if (lane == 0) {
        float contrib = logf((user ? rsU : rsI)[r]) - p * TAU_INV;
        atomicAdd(&scal[user ? 2 : 3], contrib);
    }
}

// ---------------- final scalar
__global__ void final_kernel(const float* __restrict__ scal, float* __restrict__ out, int B) {
    if (threadIdx.x == 0 && blockIdx.x == 0) {
        float invB = 1.0f / (float)B;
        float bpr_loss = scal[0] * invB + LMBD * scal[1] * invB;
        float ssl_loss = (scal[2] + scal[3]) * 0.1f;
        out[0] = bpr_loss + ssl_loss;
    }
}

extern "C" void kernel_launch(void* const* d_in, const int* in_sizes, int n_in,
                              void* d_out, int out_size, void* d_ws, size_t ws_size,
                              hipStream_t stream) {
    const float* user_emb = (const float*)d_in[0];
    const float* item_emb = (const float*)d_in[1];
    const int*   src  = (const int*)d_in[2];
    const int*   dst  = (const int*)d_in[3];
    const float* w    = (const float*)d_in[4];
    const int*   src1 = (const int*)d_in[5];
    const int*   dst1 = (const int*)d_in[6];
    const float* w1   = (const float*)d_in[7];
    const int*   src2 = (const int*)d_in[8];
    const int*   dst2 = (const int*)d_in[9];
    const float* w2   = (const float*)d_in[10];
    const int* user_id = (const int*)d_in[11];
    const int* item_id = (const int*)d_in[12];
    const int* neg_id  = (const int*)d_in[13];
    int E0 = in_sizes[2];
    int E1 = in_sizes[5];
    int E2 = in_sizes[8];
    int B  = in_sizes[11];

    size_t nd = (size_t)NN * D;
    float* hA  = (float*)d_ws;
    float* hB  = hA + nd;
    float* acc = hB + nd;
    float* ue1 = acc + nd;
    float* ie1 = ue1 + (size_t)B * D;
    float* rsU = ie1 + (size_t)B * D;
    float* rsI = rsU + B;
    float* scal = rsI + B;
    unsigned short* ue1b = (unsigned short*)ue1;
    unsigned short* ie1b = (unsigned short*)ie1;
    unsigned short* bbuf = (unsigned short*)hA;  // free after last propagation

    // zero rowsums + scalar accumulators
    hipMemsetAsync(rsU, 0, (size_t)(2 * B + 8) * sizeof(float), stream);

    int gridElem = (NN * D + 255) / 256;

    auto propagate = [&](const int* s_, const int* d_, const float* w_, int E_, int layers) {
        init_kernel<<<gridElem, 256, 0, stream>>>(user_emb, item_emb, hA, acc, hB);
        float* cur = hA;
        float* nxt = hB;
        for (int l = 0; l < layers; l++) {
            int gs = (int)(((size_t)E_ * 64 + 255) / 256);
            scatter_kernel<<<gs, 256, 0, stream>>>(cur, s_, d_, w_, nxt, E_);
            norm_acc_kernel<<<gridElem, 256, 0, stream>>>(nxt, acc, cur);
            float* t = cur; cur = nxt; nxt = t;
        }
    };

    // main graph: 4 layers -> BPR
    propagate(src, dst, w, E0, 4);
    bpr_kernel<<<(B * 64) / 256, 256, 0, stream>>>(acc, user_id, item_id, neg_id, scal, B);

    // ssl graph 1: 3 layers -> bf16 normalized sampled rows
    propagate(src1, dst1, w1, E1, 3);
    extract_norm_kernel<<<(2 * B * 64) / 256, 256, 0, stream>>>(acc, user_id, item_id, ue1b, ie1b, B);

    // ssl graph 2: 3 layers -> normalize all rows in place + bf16 copy
    propagate(src2, dst2, w2, E2, 3);
    norm_rows_bf_kernel<<<gridElem, 256, 0, stream>>>(acc, bbuf);

    // big SSL terms via MFMA (grid: colChunks x rowgroups)
    {
        dim3 gu((USER_NUM + 128 * NCITER - 1) / (128 * NCITER), 64);
        ssl_mfma_kernel<<<gu, 256, 0, stream>>>(ue1b, bbuf, rsU, USER_NUM);
        dim3 gi((ITEM_NUM + 128 * NCITER - 1) / (128 * NCITER), 64);
        ssl_mfma_kernel<<<gi, 256, 0, stream>>>(ie1b, bbuf + (size_t)USER_NUM * D, rsI, ITEM_NUM);
    }

    ssl_fin_kernel<<<(2 * B * 64) / 256, 256, 0, stream>>>(ue1b, ie1b, acc, user_id, item_id,
                                                           rsU, rsI, scal, B);
    final_kernel<<<1, 64, 0, stream>>>(scal, (float*)d_out, B);
}

// Round 5
// 2469.253 us; speedup vs baseline: 4.0933x; 2.1027x over previous
//
#include <hip/hip_runtime.h>
#include <math.h>
#include <stdint.h>

#define USER_NUM 50000
#define ITEM_NUM 100000
#define NN (USER_NUM + ITEM_NUM)
#define D 64
#define TAU_INV 2.0f   // 1/0.5
#define LMBD 0.0001f
#define NCITER 16      // ssl col-iterations per block: 128*16 = 2048 cols/block
#define NBLK ((NN + 255) / 256)

typedef __bf16 bf16x8 __attribute__((ext_vector_type(8)));
typedef float  f32x4  __attribute__((ext_vector_type(4)));

static __device__ __forceinline__ unsigned short f2bf(float x) {
    union { float f; unsigned u; } v; v.f = x;
    unsigned r = v.u + 0x7FFFu + ((v.u >> 16) & 1u);   // RNE
    return (unsigned short)(r >> 16);
}

// ---------------- init: h_cur = concat(user,item); acc = same
__global__ void init_kernel(const float* __restrict__ ue, const float* __restrict__ ie,
                            float* __restrict__ h, float* __restrict__ acc) {
    int i = blockIdx.x * 256 + threadIdx.x;
    if (i < NN * D) {
        float v = (i < USER_NUM * D) ? ue[i] : ie[i - USER_NUM * D];
        h[i] = v; acc[i] = v;
    }
}

// ---------------- CSR build: degree histogram
__global__ void deg_kernel(const int* __restrict__ dst, int* __restrict__ deg, int E) {
    int i = blockIdx.x * 256 + threadIdx.x;
    if (i < E) atomicAdd(&deg[dst[i]], 1);
}

// per-block reduce of deg (256 elems) -> bsum[block]
__global__ void scan_reduce_kernel(const int* __restrict__ deg, int* __restrict__ bsum) {
    __shared__ int sd[256];
    int tid = threadIdx.x;
    int i = blockIdx.x * 256 + tid;
    sd[tid] = (i < NN) ? deg[i] : 0;
    __syncthreads();
    for (int o = 128; o; o >>= 1) { if (tid < o) sd[tid] += sd[tid + o]; __syncthreads(); }
    if (tid == 0) bsum[blockIdx.x] = sd[0];
}

// single-block exclusive scan of bsum (nblk <= 1024); writes rowptr[NN]=total
__global__ void scan_mid_kernel(int* __restrict__ bsum, int* __restrict__ rowptr, int nblk) {
    __shared__ int sd[1024];
    int tid = threadIdx.x;
    int v = (tid < nblk) ? bsum[tid] : 0;
    sd[tid] = v;
    __syncthreads();
    for (int o = 1; o < 1024; o <<= 1) {
        int t = (tid >= o) ? sd[tid - o] : 0;
        __syncthreads();
        sd[tid] += t;
        __syncthreads();
    }
    if (tid < nblk) bsum[tid] = sd[tid] - v;   // exclusive block offsets
    if (tid == 0) rowptr[NN] = sd[1023];       // total edge count
}

// per-block exclusive scan + block offset -> rowptr, cursor
__global__ void scan_final_kernel(const int* __restrict__ deg, const int* __restrict__ bsum,
                                  int* __restrict__ rowptr, int* __restrict__ cursor) {
    __shared__ int sd[256];
    int tid = threadIdx.x;
    int i = blockIdx.x * 256 + tid;
    int v = (i < NN) ? deg[i] : 0;
    sd[tid] = v;
    __syncthreads();
    for (int o = 1; o < 256; o <<= 1) {
        int t = (tid >= o) ? sd[tid - o] : 0;
        __syncthreads();
        sd[tid] += t;
        __syncthreads();
    }
    if (i < NN) {
        int ex = sd[tid] - v + bsum[blockIdx.x];
        rowptr[i] = ex;
        cursor[i] = ex;
    }
}

// fill permuted edge list: perm[slot] = (src, w-bits), grouped by dst
__global__ void fill_kernel(const int* __restrict__ src, const int* __restrict__ dst,
                            const float* __restrict__ w, int* __restrict__ cursor,
                            int2* __restrict__ perm, int E) {
    int i = blockIdx.x * 256 + threadIdx.x;
    if (i < E) {
        int p = atomicAdd(&cursor[dst[i]], 1);
        perm[p] = make_int2(src[i], __float_as_int(w[i]));
    }
}

// ---------------- fused gather + l2-norm + acc: one wave per dst row
__global__ __launch_bounds__(256) void gather_norm_kernel(const float* __restrict__ h,
        const int* __restrict__ rowptr, const int2* __restrict__ perm,
        float* __restrict__ hn, float* __restrict__ acc) {
    int gid = blockIdx.x * 256 + threadIdx.x;
    int row = gid >> 6;
    int lane = gid & 63;
    if (row >= NN) return;
    int beg = rowptr[row];
    int end = rowptr[row + 1];
    float s = 0.f;
    int e = beg;
    for (; e + 2 <= end; e += 2) {
        int2 p0 = perm[e];
        int2 p1 = perm[e + 1];
        float v0 = h[(size_t)p0.x * D + lane];
        float v1 = h[(size_t)p1.x * D + lane];
        s += v0 * __int_as_float(p0.y);
        s += v1 * __int_as_float(p1.y);
    }
    if (e < end) {
        int2 p0 = perm[e];
        s += h[(size_t)p0.x * D + lane] * __int_as_float(p0.y);
    }
    float q = s * s;
    #pragma unroll
    for (int o = 32; o; o >>= 1) q += __shfl_xor(q, o);
    float y = s / fmaxf(sqrtf(q), 1e-12f);
    size_t idx = (size_t)row * D + lane;
    hn[idx] = y;
    acc[idx] += y;
}

// ---------------- row l2-normalize in place + write bf16 copy
__global__ void norm_rows_bf_kernel(float* __restrict__ h, unsigned short* __restrict__ hb) {
    int gid = blockIdx.x * 256 + threadIdx.x;
    int row = gid >> 6;
    int lane = gid & 63;
    if (row >= NN) return;
    size_t idx = (size_t)row * D + lane;
    float x = h[idx];
    float s = x * x;
    #pragma unroll
    for (int o = 32; o; o >>= 1) s += __shfl_xor(s, o);
    float y = x / fmaxf(sqrtf(s), 1e-12f);
    h[idx] = y;
    hb[idx] = f2bf(y);
}

// ---------------- BPR: wave per sample
__global__ void bpr_kernel(const float* __restrict__ acc, const int* __restrict__ uid,
                           const int* __restrict__ iid, const int* __restrict__ nid,
                           float* __restrict__ scal, int B) {
    int gid = blockIdx.x * 256 + threadIdx.x;
    int r = gid >> 6;
    int lane = gid & 63;
    if (r >= B) return;
    const float inv = 1.0f / 5.0f;  // MAIN_LAYERS+1
    float ue = acc[(size_t)uid[r] * D + lane] * inv;
    float pe = acc[(size_t)(USER_NUM + iid[r]) * D + lane] * inv;
    float ne = acc[(size_t)(USER_NUM + nid[r]) * D + lane] * inv;
    float pos = ue * pe, neg = ue * ne, reg = ue * ue + pe * pe + ne * ne;
    #pragma unroll
    for (int o = 32; o; o >>= 1) {
        pos += __shfl_xor(pos, o);
        neg += __shfl_xor(neg, o);
        reg += __shfl_xor(reg, o);
    }
    if (lane == 0) {
        float x = pos - neg;
        float ls = (x >= 0.f) ? (-log1pf(expf(-x))) : (x - log1pf(expf(x)));
        atomicAdd(&scal[0], -ls);
        atomicAdd(&scal[1], reg * 0.5f);
    }
}

// ---------------- extract sampled rows from acc, l2-normalize -> bf16 ue1b / ie1b
__global__ void extract_norm_kernel(const float* __restrict__ acc, const int* __restrict__ uid,
                                    const int* __restrict__ iid, unsigned short* __restrict__ ue1b,
                                    unsigned short* __restrict__ ie1b, int B) {
    int gid = blockIdx.x * 256 + threadIdx.x;
    int t = gid >> 6;
    int lane = gid & 63;
    if (t >= 2 * B) return;
    bool user = (t < B);
    int r = user ? t : (t - B);
    size_t srow = user ? (size_t)uid[r] * D : (size_t)(USER_NUM + iid[r]) * D;
    float x = acc[srow + lane];
    float s = x * x;
    #pragma unroll
    for (int o = 32; o; o >>= 1) s += __shfl_xor(s, o);
    float y = x / fmaxf(sqrtf(s), 1e-12f);
    (user ? ue1b : ie1b)[(size_t)r * D + lane] = f2bf(y);
}

// ---------------- big SSL via MFMA: register accumulation, atomics only at end
__global__ __launch_bounds__(256) void ssl_mfma_kernel(const unsigned short* __restrict__ Ab,
                                                       const unsigned short* __restrict__ Bb,
                                                       float* __restrict__ rowsum, int M) {
    int wave = threadIdx.x >> 6;
    int lane = threadIdx.x & 63;
    int l15 = lane & 15;
    int lg  = lane >> 4;
    int rgbase = blockIdx.y * 64;
    int chunkbase = blockIdx.x * (128 * NCITER);

    bf16x8 afr[4][2];
    {
        const unsigned short* ab = Ab + (size_t)(rgbase + l15) * D + lg * 8;
        #pragma unroll
        for (int i = 0; i < 4; i++) {
            afr[i][0] = *(const bf16x8*)(ab + (size_t)i * 16 * D);
            afr[i][1] = *(const bf16x8*)(ab + (size_t)i * 16 * D + 32);
        }
    }

    float rowacc[4][4];
    #pragma unroll
    for (int i = 0; i < 4; i++)
        #pragma unroll
        for (int r = 0; r < 4; r++) rowacc[i][r] = 0.f;

    for (int it = 0; it < NCITER; it++) {
        int cb = chunkbase + it * 128 + wave * 32;
        bf16x8 bfr[2][2];
        bool val[2];
        #pragma unroll
        for (int cf = 0; cf < 2; cf++) {
            int col = cb + cf * 16 + l15;
            val[cf] = (col < M);
            int cc = val[cf] ? col : (M - 1);
            const unsigned short* bp = Bb + (size_t)cc * D + lg * 8;
            bfr[cf][0] = *(const bf16x8*)(bp);
            bfr[cf][1] = *(const bf16x8*)(bp + 32);
        }

        f32x4 acc[4][2];
        #pragma unroll
        for (int i = 0; i < 4; i++)
            #pragma unroll
            for (int cf = 0; cf < 2; cf++)
                acc[i][cf] = (f32x4){0.f, 0.f, 0.f, 0.f};

        #pragma unroll
        for (int i = 0; i < 4; i++) {
            #pragma unroll
            for (int cf = 0; cf < 2; cf++) {
                acc[i][cf] = __builtin_amdgcn_mfma_f32_16x16x32_bf16(afr[i][0], bfr[cf][0], acc[i][cf], 0, 0, 0);
                acc[i][cf] = __builtin_amdgcn_mfma_f32_16x16x32_bf16(afr[i][1], bfr[cf][1], acc[i][cf], 0, 0, 0);
            }
        }

        #pragma unroll
        for (int i = 0; i < 4; i++) {
            #pragma unroll
            for (int r = 0; r < 4; r++) {
                float e0 = val[0] ? __expf(TAU_INV * acc[i][0][r]) : 0.f;
                float e1 = val[1] ? __expf(TAU_INV * acc[i][1][r]) : 0.f;
                rowacc[i][r] += e0 + e1;
            }
        }
    }

    #pragma unroll
    for (int i = 0; i < 4; i++) {
        #pragma unroll
        for (int r = 0; r < 4; r++) {
            float s = rowacc[i][r];
            s += __shfl_xor(s, 1);
            s += __shfl_xor(s, 2);
            s += __shfl_xor(s, 4);
            s += __shfl_xor(s, 8);
            if (l15 == 0) atomicAdd(&rowsum[rgbase + i * 16 + lg * 4 + r], s);
        }
    }
}

// ---------------- SSL finalize
__global__ void ssl_fin_kernel(const unsigned short* __restrict__ ue1b,
                               const unsigned short* __restrict__ ie1b,
                               const float* __restrict__ A2, const int* __restrict__ uid,
                               const int* __restrict__ iid, const float* __restrict__ rsU,
                               const float* __restrict__ rsI, float* __restrict__ scal, int B) {
    int gid = blockIdx.x * 256 + threadIdx.x;
    int t = gid >> 6;
    int lane = gid & 63;
    if (t >= 2 * B) return;
    bool user = (t < B);
    int r = user ? t : (t - B);
    const unsigned short* a = (user ? ue1b : ie1b) + (size_t)r * D;
    size_t brow = user ? (size_t)uid[r] * D : (size_t)(USER_NUM + iid[r]) * D;
    union { unsigned u; float f; } cv; cv.u = ((unsigned)a[lane]) << 16;
    float p = cv.f * A2[brow + lane];
    #pragma unroll
    for (int o = 32; o; o >>= 1) p += __shfl_xor(p, o);
    if (lane == 0) {
        float contrib = logf((user ? rsU : rsI)[r]) - p * TAU_INV;
        atomicAdd(&scal[user ? 2 : 3], contrib);
    }
}

// ---------------- final scalar
__global__ void final_kernel(const float* __restrict__ scal, float* __restrict__ out, int B) {
    if (threadIdx.x == 0 && blockIdx.x == 0) {
        float invB = 1.0f / (float)B;
        float bpr_loss = scal[0] * invB + LMBD * scal[1] * invB;
        float ssl_loss = (scal[2] + scal[3]) * 0.1f;
        out[0] = bpr_loss + ssl_loss;
    }
}

extern "C" void kernel_launch(void* const* d_in, const int* in_sizes, int n_in,
                              void* d_out, int out_size, void* d_ws, size_t ws_size,
                              hipStream_t stream) {
    const float* user_emb = (const float*)d_in[0];
    const float* item_emb = (const float*)d_in[1];
    const int*   src  = (const int*)d_in[2];
    const int*   dst  = (const int*)d_in[3];
    const float* w    = (const float*)d_in[4];
    const int*   src1 = (const int*)d_in[5];
    const int*   dst1 = (const int*)d_in[6];
    const float* w1   = (const float*)d_in[7];
    const int*   src2 = (const int*)d_in[8];
    const int*   dst2 = (const int*)d_in[9];
    const float* w2   = (const float*)d_in[10];
    const int* user_id = (const int*)d_in[11];
    const int* item_id = (const int*)d_in[12];
    const int* neg_id  = (const int*)d_in[13];
    int E0 = in_sizes[2];
    int E1 = in_sizes[5];
    int E2 = in_sizes[8];
    int B  = in_sizes[11];

    size_t nd = (size_t)NN * D;
    float* hA  = (float*)d_ws;
    float* hB  = hA + nd;
    float* acc = hB + nd;
    float* ue1 = acc + nd;
    float* ie1 = ue1 + (size_t)B * D;
    float* rsU = ie1 + (size_t)B * D;
    float* rsI = rsU + B;
    float* scal = rsI + B;                 // 8 floats
    int* deg    = (int*)(scal + 8);
    int* rowptr = deg + NN;                // NN+1 entries
    int* cursor = rowptr + NN + 1;
    int* bsum   = cursor + NN;             // NBLK entries
    int2* perm  = (int2*)(((uintptr_t)(bsum + NBLK) + 15) & ~(uintptr_t)15);
    unsigned short* ue1b = (unsigned short*)ue1;
    unsigned short* ie1b = (unsigned short*)ie1;
    unsigned short* bbuf = (unsigned short*)hA;  // free after last propagation

    hipMemsetAsync(rsU, 0, (size_t)(2 * B + 8) * sizeof(float), stream);

    int gridElem = (NN * D + 255) / 256;     // elementwise over N*D
    int gridRows = (NN * 64 + 255) / 256;    // wave per row

    auto propagate = [&](const int* s_, const int* d_, const float* w_, int E_, int layers) {
        // --- build CSR (grouped by dst)
        hipMemsetAsync(deg, 0, (size_t)NN * sizeof(int), stream);
        int ge = (E_ + 255) / 256;
        deg_kernel<<<ge, 256, 0, stream>>>(d_, deg, E_);
        scan_reduce_kernel<<<NBLK, 256, 0, stream>>>(deg, bsum);
        scan_mid_kernel<<<1, 1024, 0, stream>>>(bsum, rowptr, NBLK);
        scan_final_kernel<<<NBLK, 256, 0, stream>>>(deg, bsum, rowptr, cursor);
        fill_kernel<<<ge, 256, 0, stream>>>(s_, d_, w_, cursor, perm, E_);
        // --- layers
        init_kernel<<<gridElem, 256, 0, stream>>>(user_emb, item_emb, hA, acc);
        float* cur = hA;
        float* nxt = hB;
        for (int l = 0; l < layers; l++) {
            gather_norm_kernel<<<gridRows, 256, 0, stream>>>(cur, rowptr, perm, nxt, acc);
            float* t = cur; cur = nxt; nxt = t;
        }
    };

    // main graph: 4 layers -> BPR
    propagate(src, dst, w, E0, 4);
    bpr_kernel<<<(B * 64) / 256, 256, 0, stream>>>(acc, user_id, item_id, neg_id, scal, B);

    // ssl graph 1: 3 layers -> bf16 normalized sampled rows
    propagate(src1, dst1, w1, E1, 3);
    extract_norm_kernel<<<(2 * B * 64) / 256, 256, 0, stream>>>(acc, user_id, item_id, ue1b, ie1b, B);

    // ssl graph 2: 3 layers -> normalize all rows in place + bf16 copy
    propagate(src2, dst2, w2, E2, 3);
    norm_rows_bf_kernel<<<gridRows, 256, 0, stream>>>(acc, bbuf);

    // big SSL terms via MFMA (grid: colChunks x rowgroups)
    {
        dim3 gu((USER_NUM + 128 * NCITER - 1) / (128 * NCITER), 64);
        ssl_mfma_kernel<<<gu, 256, 0, stream>>>(ue1b, bbuf, rsU, USER_NUM);
        dim3 gi((ITEM_NUM + 128 * NCITER - 1) / (128 * NCITER), 64);
        ssl_mfma_kernel<<<gi, 256, 0, stream>>>(ie1b, bbuf + (size_t)USER_NUM * D, rsI, ITEM_NUM);
    }

    ssl_fin_kernel<<<(2 * B * 64) / 256, 256, 0, stream>>>(ue1b, ie1b, acc, user_id, item_id,
                                                           rsU, rsI, scal, B);
    final_kernel<<<1, 64, 0, stream>>>(scal, (float*)d_out, B);
}

// Round 6
// 2400.882 us; speedup vs baseline: 4.2099x; 1.0285x over previous
//
#include <hip/hip_runtime.h>
#include <math.h>
#include <stdint.h>

#define USER_NUM 50000
#define ITEM_NUM 100000
#define NN (USER_NUM + ITEM_NUM)
#define D 64
#define TAU_INV 2.0f   // 1/0.5
#define LMBD 0.0001f
#define NCITER 16      // ssl col-iterations per block: 128*16 = 2048 cols/chunk
#define NRG 64         // ssl rowgroups (4096 A-rows / 64)
#define NBLK ((NN + 255) / 256)

typedef __bf16 bf16x8 __attribute__((ext_vector_type(8)));
typedef float  f32x4  __attribute__((ext_vector_type(4)));

static __device__ __forceinline__ unsigned short f2bf(float x) {
    union { float f; unsigned u; } v; v.f = x;
    unsigned r = v.u + 0x7FFFu + ((v.u >> 16) & 1u);   // RNE
    return (unsigned short)(r >> 16);
}
static __device__ __forceinline__ float bf2f(unsigned short b) {
    union { unsigned u; float f; } v; v.u = ((unsigned)b) << 16;
    return v.f;
}

// ---------------- init: hb = bf16(concat(user,item)); acc = fp32 same
__global__ void init_kernel(const float* __restrict__ ue, const float* __restrict__ ie,
                            unsigned short* __restrict__ hb, float* __restrict__ acc) {
    int i = blockIdx.x * 256 + threadIdx.x;
    if (i < NN * D) {
        float v = (i < USER_NUM * D) ? ue[i] : ie[i - USER_NUM * D];
        hb[i] = f2bf(v); acc[i] = v;
    }
}

// ---------------- CSR build: degree histogram
__global__ void deg_kernel(const int* __restrict__ dst, int* __restrict__ deg, int E) {
    int i = blockIdx.x * 256 + threadIdx.x;
    if (i < E) atomicAdd(&deg[dst[i]], 1);
}

__global__ void scan_reduce_kernel(const int* __restrict__ deg, int* __restrict__ bsum) {
    __shared__ int sd[256];
    int tid = threadIdx.x;
    int i = blockIdx.x * 256 + tid;
    sd[tid] = (i < NN) ? deg[i] : 0;
    __syncthreads();
    for (int o = 128; o; o >>= 1) { if (tid < o) sd[tid] += sd[tid + o]; __syncthreads(); }
    if (tid == 0) bsum[blockIdx.x] = sd[0];
}

__global__ void scan_mid_kernel(int* __restrict__ bsum, int* __restrict__ rowptr, int nblk) {
    __shared__ int sd[1024];
    int tid = threadIdx.x;
    int v = (tid < nblk) ? bsum[tid] : 0;
    sd[tid] = v;
    __syncthreads();
    for (int o = 1; o < 1024; o <<= 1) {
        int t = (tid >= o) ? sd[tid - o] : 0;
        __syncthreads();
        sd[tid] += t;
        __syncthreads();
    }
    if (tid < nblk) bsum[tid] = sd[tid] - v;
    if (tid == 0) rowptr[NN] = sd[1023];
}

__global__ void scan_final_kernel(const int* __restrict__ deg, const int* __restrict__ bsum,
                                  int* __restrict__ rowptr, int* __restrict__ cursor) {
    __shared__ int sd[256];
    int tid = threadIdx.x;
    int i = blockIdx.x * 256 + tid;
    int v = (i < NN) ? deg[i] : 0;
    sd[tid] = v;
    __syncthreads();
    for (int o = 1; o < 256; o <<= 1) {
        int t = (tid >= o) ? sd[tid - o] : 0;
        __syncthreads();
        sd[tid] += t;
        __syncthreads();
    }
    if (i < NN) {
        int ex = sd[tid] - v + bsum[blockIdx.x];
        rowptr[i] = ex;
        cursor[i] = ex;
    }
}

__global__ void fill_kernel(const int* __restrict__ src, const int* __restrict__ dst,
                            const float* __restrict__ w, int* __restrict__ cursor,
                            int2* __restrict__ perm, int E) {
    int i = blockIdx.x * 256 + threadIdx.x;
    if (i < E) {
        int p = atomicAdd(&cursor[dst[i]], 1);
        perm[p] = make_int2(src[i], __float_as_int(w[i]));
    }
}

// ---------------- fused gather(bf16) + l2-norm + acc: one wave per dst row
__global__ __launch_bounds__(256) void gather_norm_kernel(const unsigned short* __restrict__ hb,
        const int* __restrict__ rowptr, const int2* __restrict__ perm,
        unsigned short* __restrict__ hn, float* __restrict__ acc) {
    int gid = blockIdx.x * 256 + threadIdx.x;
    int row = gid >> 6;
    int lane = gid & 63;
    if (row >= NN) return;
    int beg = rowptr[row];
    int end = rowptr[row + 1];
    float s = 0.f;
    int e = beg;
    for (; e + 2 <= end; e += 2) {
        int2 p0 = perm[e];
        int2 p1 = perm[e + 1];
        float v0 = bf2f(hb[(size_t)p0.x * D + lane]);
        float v1 = bf2f(hb[(size_t)p1.x * D + lane]);
        s += v0 * __int_as_float(p0.y);
        s += v1 * __int_as_float(p1.y);
    }
    if (e < end) {
        int2 p0 = perm[e];
        s += bf2f(hb[(size_t)p0.x * D + lane]) * __int_as_float(p0.y);
    }
    float q = s * s;
    #pragma unroll
    for (int o = 32; o; o >>= 1) q += __shfl_xor(q, o);
    float y = s / fmaxf(sqrtf(q), 1e-12f);
    size_t idx = (size_t)row * D + lane;
    hn[idx] = f2bf(y);
    acc[idx] += y;
}

// ---------------- row l2-normalize acc in place + write bf16 copy
__global__ void norm_rows_bf_kernel(float* __restrict__ h, unsigned short* __restrict__ hb) {
    int gid = blockIdx.x * 256 + threadIdx.x;
    int row = gid >> 6;
    int lane = gid & 63;
    if (row >= NN) return;
    size_t idx = (size_t)row * D + lane;
    float x = h[idx];
    float s = x * x;
    #pragma unroll
    for (int o = 32; o; o >>= 1) s += __shfl_xor(s, o);
    float y = x / fmaxf(sqrtf(s), 1e-12f);
    h[idx] = y;
    hb[idx] = f2bf(y);
}

// ---------------- BPR: wave per sample
__global__ void bpr_kernel(const float* __restrict__ acc, const int* __restrict__ uid,
                           const int* __restrict__ iid, const int* __restrict__ nid,
                           float* __restrict__ scal, int B) {
    int gid = blockIdx.x * 256 + threadIdx.x;
    int r = gid >> 6;
    int lane = gid & 63;
    if (r >= B) return;
    const float inv = 1.0f / 5.0f;  // MAIN_LAYERS+1
    float ue = acc[(size_t)uid[r] * D + lane] * inv;
    float pe = acc[(size_t)(USER_NUM + iid[r]) * D + lane] * inv;
    float ne = acc[(size_t)(USER_NUM + nid[r]) * D + lane] * inv;
    float pos = ue * pe, neg = ue * ne, reg = ue * ue + pe * pe + ne * ne;
    #pragma unroll
    for (int o = 32; o; o >>= 1) {
        pos += __shfl_xor(pos, o);
        neg += __shfl_xor(neg, o);
        reg += __shfl_xor(reg, o);
    }
    if (lane == 0) {
        float x = pos - neg;
        float ls = (x >= 0.f) ? (-log1pf(expf(-x))) : (x - log1pf(expf(x)));
        atomicAdd(&scal[0], -ls);
        atomicAdd(&scal[1], reg * 0.5f);
    }
}

// ---------------- extract sampled rows from acc, l2-normalize -> bf16
__global__ void extract_norm_kernel(const float* __restrict__ acc, const int* __restrict__ uid,
                                    const int* __restrict__ iid, unsigned short* __restrict__ ue1b,
                                    unsigned short* __restrict__ ie1b, int B) {
    int gid = blockIdx.x * 256 + threadIdx.x;
    int t = gid >> 6;
    int lane = gid & 63;
    if (t >= 2 * B) return;
    bool user = (t < B);
    int r = user ? t : (t - B);
    size_t srow = user ? (size_t)uid[r] * D : (size_t)(USER_NUM + iid[r]) * D;
    float x = acc[srow + lane];
    float s = x * x;
    #pragma unroll
    for (int o = 32; o; o >>= 1) s += __shfl_xor(s, o);
    float y = x / fmaxf(sqrtf(s), 1e-12f);
    (user ? ue1b : ie1b)[(size_t)r * D + lane] = f2bf(y);
}

// ---------------- big SSL via MFMA, XCD-locality grid.
// 1-D grid, size 8*NRG*ceil(nc/8). Decode so all NRG rowgroup-blocks of one
// col-chunk get blockIdx ≡ same (mod 8) -> same XCD -> B chunk (256KB) stays
// in that XCD's L2 instead of being re-fetched 64x from HBM.
__global__ __launch_bounds__(256) void ssl_mfma_kernel(const unsigned short* __restrict__ Ab,
                                                       const unsigned short* __restrict__ Bb,
                                                       float* __restrict__ rowsum,
                                                       int M, int nc) {
    int bid = blockIdx.x;
    int xcd = bid & 7;
    int inner = bid >> 3;
    int rg = inner & (NRG - 1);
    int cgrp = inner >> 6;
    int colChunk = cgrp * 8 + xcd;
    if (colChunk >= nc) return;

    int wave = threadIdx.x >> 6;
    int lane = threadIdx.x & 63;
    int l15 = lane & 15;
    int lg  = lane >> 4;
    int rgbase = rg * 64;
    int chunkbase = colChunk * (128 * NCITER);

    bf16x8 afr[4][2];
    {
        const unsigned short* ab = Ab + (size_t)(rgbase + l15) * D + lg * 8;
        #pragma unroll
        for (int i = 0; i < 4; i++) {
            afr[i][0] = *(const bf16x8*)(ab + (size_t)i * 16 * D);
            afr[i][1] = *(const bf16x8*)(ab + (size_t)i * 16 * D + 32);
        }
    }

    float rowacc[4][4];
    #pragma unroll
    for (int i = 0; i < 4; i++)
        #pragma unroll
        for (int r = 0; r < 4; r++) rowacc[i][r] = 0.f;

    for (int it = 0; it < NCITER; it++) {
        int cb = chunkbase + it * 128 + wave * 32;
        bf16x8 bfr[2][2];
        bool val[2];
        #pragma unroll
        for (int cf = 0; cf < 2; cf++) {
            int col = cb + cf * 16 + l15;
            val[cf] = (col < M);
            int cc = val[cf] ? col : (M - 1);
            const unsigned short* bp = Bb + (size_t)cc * D + lg * 8;
            bfr[cf][0] = *(const bf16x8*)(bp);
            bfr[cf][1] = *(const bf16x8*)(bp + 32);
        }

        f32x4 acc[4][2];
        #pragma unroll
        for (int i = 0; i < 4; i++)
            #pragma unroll
            for (int cf = 0; cf < 2; cf++)
                acc[i][cf] = (f32x4){0.f, 0.f, 0.f, 0.f};

        #pragma unroll
        for (int i = 0; i < 4; i++) {
            #pragma unroll
            for (int cf = 0; cf < 2; cf++) {
                acc[i][cf] = __builtin_amdgcn_mfma_f32_16x16x32_bf16(afr[i][0], bfr[cf][0], acc[i][cf], 0, 0, 0);
                acc[i][cf] = __builtin_amdgcn_mfma_f32_16x16x32_bf16(afr[i][1], bfr[cf][1], acc[i][cf], 0, 0, 0);
            }
        }

        #pragma unroll
        for (int i = 0; i < 4; i++) {
            #pragma unroll
            for (int r = 0; r < 4; r++) {
                float e0 = val[0] ? __expf(TAU_INV * acc[i][0][r]) : 0.f;
                float e1 = val[1] ? __expf(TAU_INV * acc[i][1][r]) : 0.f;
                rowacc[i][r] += e0 + e1;
            }
        }
    }

    #pragma unroll
    for (int i = 0; i < 4; i++) {
        #pragma unroll
        for (int r = 0; r < 4; r++) {
            float s = rowacc[i][r];
            s += __shfl_xor(s, 1);
            s += __shfl_xor(s, 2);
            s += __shfl_xor(s, 4);
            s += __shfl_xor(s, 8);
            if (l15 == 0) atomicAdd(&rowsum[rgbase + i * 16 + lg * 4 + r], s);
        }
    }
}

// ---------------- SSL finalize
__global__ void ssl_fin_kernel(const unsigned short* __restrict__ ue1b,
                               const unsigned short* __restrict__ ie1b,
                               const float* __restrict__ A2, const int* __restrict__ uid,
                               const int* __restrict__ iid, const float* __restrict__ rsU,
                               const float* __restrict__ rsI, float* __restrict__ scal, int B) {
    int gid = blockIdx.x * 256 + threadIdx.x;
    int t = gid >> 6;
    int lane = gid & 63;
    if (t >= 2 * B) return;
    bool user = (t < B);
    int r = user ? t : (t - B);
    const unsigned short* a = (user ? ue1b : ie1b) + (size_t)r * D;
    size_t brow = user ? (size_t)uid[r] * D : (size_t)(USER_NUM + iid[r]) * D;
    float p = bf2f(a[lane]) * A2[brow + lane];
    #pragma unroll
    for (int o = 32; o; o >>= 1) p += __shfl_xor(p, o);
    if (lane == 0) {
        float contrib = logf((user ? rsU : rsI)[r]) - p * TAU_INV;
        atomicAdd(&scal[user ? 2 : 3], contrib);
    }
}

// ---------------- final scalar
__global__ void final_kernel(const float* __restrict__ scal, float* __restrict__ out, int B) {
    if (threadIdx.x == 0 && blockIdx.x == 0) {
        float invB = 1.0f / (float)B;
        float bpr_loss = scal[0] * invB + LMBD * scal[1] * invB;
        float ssl_loss = (scal[2] + scal[3]) * 0.1f;
        out[0] = bpr_loss + ssl_loss;
    }
}

extern "C" void kernel_launch(void* const* d_in, const int* in_sizes, int n_in,
                              void* d_out, int out_size, void* d_ws, size_t ws_size,
                              hipStream_t stream) {
    const float* user_emb = (const float*)d_in[0];
    const float* item_emb = (const float*)d_in[1];
    const int*   src  = (const int*)d_in[2];
    const int*   dst  = (const int*)d_in[3];
    const float* w    = (const float*)d_in[4];
    const int*   src1 = (const int*)d_in[5];
    const int*   dst1 = (const int*)d_in[6];
    const float* w1   = (const float*)d_in[7];
    const int*   src2 = (const int*)d_in[8];
    const int*   dst2 = (const int*)d_in[9];
    const float* w2   = (const float*)d_in[10];
    const int* user_id = (const int*)d_in[11];
    const int* item_id = (const int*)d_in[12];
    const int* neg_id  = (const int*)d_in[13];
    int E0 = in_sizes[2];
    int E1 = in_sizes[5];
    int E2 = in_sizes[8];
    int B  = in_sizes[11];

    size_t nd = (size_t)NN * D;
    float* acc = (float*)d_ws;                       // fp32 NN*D
    unsigned short* hAb = (unsigned short*)(acc + nd);
    unsigned short* hBb = hAb + nd;
    unsigned short* ue1b = hBb + nd;
    unsigned short* ie1b = ue1b + (size_t)B * D;
    float* rsU  = (float*)(ie1b + (size_t)B * D);
    float* rsI  = rsU + B;
    float* scal = rsI + B;                 // 8 floats
    int* deg    = (int*)(scal + 8);
    int* rowptr = deg + NN;                // NN+1
    int* cursor = rowptr + NN + 1;
    int* bsum   = cursor + NN;             // NBLK
    int2* perm  = (int2*)(((uintptr_t)(bsum + NBLK) + 15) & ~(uintptr_t)15);
    unsigned short* bbuf = hAb;            // reuse after last propagation

    hipMemsetAsync(rsU, 0, (size_t)(2 * B + 8) * sizeof(float), stream);

    int gridElem = (NN * D + 255) / 256;
    int gridRows = (NN * 64 + 255) / 256;

    auto propagate = [&](const int* s_, const int* d_, const float* w_, int E_, int layers) {
        hipMemsetAsync(deg, 0, (size_t)NN * sizeof(int), stream);
        int ge = (E_ + 255) / 256;
        deg_kernel<<<ge, 256, 0, stream>>>(d_, deg, E_);
        scan_reduce_kernel<<<NBLK, 256, 0, stream>>>(deg, bsum);
        scan_mid_kernel<<<1, 1024, 0, stream>>>(bsum, rowptr, NBLK);
        scan_final_kernel<<<NBLK, 256, 0, stream>>>(deg, bsum, rowptr, cursor);
        fill_kernel<<<ge, 256, 0, stream>>>(s_, d_, w_, cursor, perm, E_);
        init_kernel<<<gridElem, 256, 0, stream>>>(user_emb, item_emb, hAb, acc);
        unsigned short* cur = hAb;
        unsigned short* nxt = hBb;
        for (int l = 0; l < layers; l++) {
            gather_norm_kernel<<<gridRows, 256, 0, stream>>>(cur, rowptr, perm, nxt, acc);
            unsigned short* t = cur; cur = nxt; nxt = t;
        }
    };

    // main graph: 4 layers -> BPR
    propagate(src, dst, w, E0, 4);
    bpr_kernel<<<(B * 64) / 256, 256, 0, stream>>>(acc, user_id, item_id, neg_id, scal, B);

    // ssl graph 1: 3 layers -> bf16 normalized sampled rows
    propagate(src1, dst1, w1, E1, 3);
    extract_norm_kernel<<<(2 * B * 64) / 256, 256, 0, stream>>>(acc, user_id, item_id, ue1b, ie1b, B);

    // ssl graph 2: 3 layers -> normalize acc in place + bf16 copy
    propagate(src2, dst2, w2, E2, 3);
    norm_rows_bf_kernel<<<gridRows, 256, 0, stream>>>(acc, bbuf);

    // big SSL terms via MFMA (XCD-locality 1-D grid)
    {
        int ncU = (USER_NUM + 128 * NCITER - 1) / (128 * NCITER);
        int gu = 8 * NRG * ((ncU + 7) / 8);
        ssl_mfma_kernel<<<gu, 256, 0, stream>>>(ue1b, bbuf, rsU, USER_NUM, ncU);
        int ncI = (ITEM_NUM + 128 * NCITER - 1) / (128 * NCITER);
        int gi = 8 * NRG * ((ncI + 7) / 8);
        ssl_mfma_kernel<<<gi, 256, 0, stream>>>(ie1b, bbuf + (size_t)USER_NUM * D, rsI, ITEM_NUM, ncI);
    }

    ssl_fin_kernel<<<(2 * B * 64) / 256, 256, 0, stream>>>(ue1b, ie1b, acc, user_id, item_id,
                                                           rsU, rsI, scal, B);
    final_kernel<<<1, 64, 0, stream>>>(scal, (float*)d_out, B);
}

// Round 7
// 2044.586 us; speedup vs baseline: 4.9435x; 1.1743x over previous
//
#include <hip/hip_runtime.h>
#include <math.h>
#include <stdint.h>

#define USER_NUM 50000
#define ITEM_NUM 100000
#define NN (USER_NUM + ITEM_NUM)
#define D 64
#define TAU_INV 2.0f   // 1/0.5
#define LMBD 0.0001f
#define NCITER 16      // ssl col-iterations per block: 128*16 = 2048 cols/chunk
#define NRG 64         // ssl rowgroups (4096 A-rows / 64)
#define T3 (3 * NN)
#define NBLK3 ((T3 + 255) / 256)

typedef __bf16 bf16x8 __attribute__((ext_vector_type(8)));
typedef float  f32x4  __attribute__((ext_vector_type(4)));

static __device__ __forceinline__ unsigned short f2bf(float x) {
    union { float f; unsigned u; } v; v.f = x;
    unsigned r = v.u + 0x7FFFu + ((v.u >> 16) & 1u);   // RNE
    return (unsigned short)(r >> 16);
}
static __device__ __forceinline__ float bf2f(unsigned short b) {
    union { unsigned u; float f; } v; v.u = ((unsigned)b) << 16;
    return v.f;
}

// ---------------- init: hb = bf16(concat(user,item)); acc = fp32 same
__global__ void init_kernel(const float* __restrict__ ue, const float* __restrict__ ie,
                            unsigned short* __restrict__ hb, float* __restrict__ acc) {
    int i = blockIdx.x * 256 + threadIdx.x;
    if (i < NN * D) {
        float v = (i < USER_NUM * D) ? ue[i] : ie[i - USER_NUM * D];
        hb[i] = f2bf(v); acc[i] = v;
    }
}

// ---------------- fused CSR build over 3 graphs (node id offset g*NN)
__global__ void deg3_kernel(const int* __restrict__ d0, const int* __restrict__ d1,
                            const int* __restrict__ d2, int* __restrict__ deg3,
                            int E0, int E1, int E2) {
    int i = blockIdx.x * 256 + threadIdx.x;
    int d;
    if (i < E0) d = d0[i];
    else if (i < E0 + E1) d = NN + d1[i - E0];
    else if (i < E0 + E1 + E2) d = 2 * NN + d2[i - E0 - E1];
    else return;
    atomicAdd(&deg3[d], 1);
}

__global__ void scan_reduce_kernel(const int* __restrict__ deg, int* __restrict__ bsum) {
    __shared__ int sd[256];
    int tid = threadIdx.x;
    int i = blockIdx.x * 256 + tid;
    sd[tid] = (i < T3) ? deg[i] : 0;
    __syncthreads();
    for (int o = 128; o; o >>= 1) { if (tid < o) sd[tid] += sd[tid + o]; __syncthreads(); }
    if (tid == 0) bsum[blockIdx.x] = sd[0];
}

// single-block scan of up to 2048 block-sums (2 per thread); writes total -> *totp
__global__ void scan_mid_kernel(int* __restrict__ bsum, int* __restrict__ totp, int nblk) {
    __shared__ int sd[1024];
    int tid = threadIdx.x;
    int v0 = (2 * tid < nblk) ? bsum[2 * tid] : 0;
    int v1 = (2 * tid + 1 < nblk) ? bsum[2 * tid + 1] : 0;
    sd[tid] = v0 + v1;
    __syncthreads();
    for (int o = 1; o < 1024; o <<= 1) {
        int t = (tid >= o) ? sd[tid - o] : 0;
        __syncthreads();
        sd[tid] += t;
        __syncthreads();
    }
    int base = tid ? sd[tid - 1] : 0;   // exclusive base of this pair
    if (2 * tid < nblk) bsum[2 * tid] = base;
    if (2 * tid + 1 < nblk) bsum[2 * tid + 1] = base + v0;
    if (tid == 1023) totp[0] = sd[1023];
}

__global__ void scan_final_kernel(const int* __restrict__ deg, const int* __restrict__ bsum,
                                  int* __restrict__ rowptr, int* __restrict__ cursor) {
    __shared__ int sd[256];
    int tid = threadIdx.x;
    int i = blockIdx.x * 256 + tid;
    int v = (i < T3) ? deg[i] : 0;
    sd[tid] = v;
    __syncthreads();
    for (int o = 1; o < 256; o <<= 1) {
        int t = (tid >= o) ? sd[tid - o] : 0;
        __syncthreads();
        sd[tid] += t;
        __syncthreads();
    }
    if (i < T3) {
        int ex = sd[tid] - v + bsum[blockIdx.x];
        rowptr[i] = ex;
        cursor[i] = ex;
    }
}

__global__ void fill3_kernel(const int* __restrict__ s0, const int* __restrict__ d0, const float* __restrict__ w0,
                             const int* __restrict__ s1, const int* __restrict__ d1, const float* __restrict__ w1,
                             const int* __restrict__ s2, const int* __restrict__ d2, const float* __restrict__ w2,
                             int* __restrict__ cursor, int2* __restrict__ perm,
                             int E0, int E1, int E2) {
    int i = blockIdx.x * 256 + threadIdx.x;
    int d, s; float w;
    if (i < E0) { d = d0[i]; s = s0[i]; w = w0[i]; }
    else if (i < E0 + E1) { int j = i - E0; d = NN + d1[j]; s = s1[j]; w = w1[j]; }
    else if (i < E0 + E1 + E2) { int j = i - E0 - E1; d = 2 * NN + d2[j]; s = s2[j]; w = w2[j]; }
    else return;
    int p = atomicAdd(&cursor[d], 1);
    perm[p] = make_int2(s, __float_as_int(w));
}

// ---------------- fused gather(bf16) + l2-norm + acc: one wave per dst row, 4x unroll
__global__ __launch_bounds__(256) void gather_norm_kernel(const unsigned short* __restrict__ hb,
        const int* __restrict__ rowptr, const int2* __restrict__ perm,
        unsigned short* __restrict__ hn, float* __restrict__ acc) {
    int gid = blockIdx.x * 256 + threadIdx.x;
    int row = gid >> 6;
    int lane = gid & 63;
    if (row >= NN) return;
    int beg = rowptr[row];
    int end = rowptr[row + 1];
    float s = 0.f;
    int e = beg;
    for (; e + 4 <= end; e += 4) {
        int2 p0 = perm[e];
        int2 p1 = perm[e + 1];
        int2 p2 = perm[e + 2];
        int2 p3 = perm[e + 3];
        float v0 = bf2f(hb[(size_t)p0.x * D + lane]);
        float v1 = bf2f(hb[(size_t)p1.x * D + lane]);
        float v2 = bf2f(hb[(size_t)p2.x * D + lane]);
        float v3 = bf2f(hb[(size_t)p3.x * D + lane]);
        s += v0 * __int_as_float(p0.y) + v1 * __int_as_float(p1.y)
           + v2 * __int_as_float(p2.y) + v3 * __int_as_float(p3.y);
    }
    for (; e < end; e++) {
        int2 p0 = perm[e];
        s += bf2f(hb[(size_t)p0.x * D + lane]) * __int_as_float(p0.y);
    }
    float q = s * s;
    #pragma unroll
    for (int o = 32; o; o >>= 1) q += __shfl_xor(q, o);
    float y = s / fmaxf(sqrtf(q), 1e-12f);
    size_t idx = (size_t)row * D + lane;
    hn[idx] = f2bf(y);
    acc[idx] += y;
}

// ---------------- row l2-normalize acc in place + write bf16 copy
__global__ void norm_rows_bf_kernel(float* __restrict__ h, unsigned short* __restrict__ hb) {
    int gid = blockIdx.x * 256 + threadIdx.x;
    int row = gid >> 6;
    int lane = gid & 63;
    if (row >= NN) return;
    size_t idx = (size_t)row * D + lane;
    float x = h[idx];
    float s = x * x;
    #pragma unroll
    for (int o = 32; o; o >>= 1) s += __shfl_xor(s, o);
    float y = x / fmaxf(sqrtf(s), 1e-12f);
    h[idx] = y;
    hb[idx] = f2bf(y);
}

// ---------------- BPR: wave per sample
__global__ void bpr_kernel(const float* __restrict__ acc, const int* __restrict__ uid,
                           const int* __restrict__ iid, const int* __restrict__ nid,
                           float* __restrict__ scal, int B) {
    int gid = blockIdx.x * 256 + threadIdx.x;
    int r = gid >> 6;
    int lane = gid & 63;
    if (r >= B) return;
    const float inv = 1.0f / 5.0f;  // MAIN_LAYERS+1
    float ue = acc[(size_t)uid[r] * D + lane] * inv;
    float pe = acc[(size_t)(USER_NUM + iid[r]) * D + lane] * inv;
    float ne = acc[(size_t)(USER_NUM + nid[r]) * D + lane] * inv;
    float pos = ue * pe, neg = ue * ne, reg = ue * ue + pe * pe + ne * ne;
    #pragma unroll
    for (int o = 32; o; o >>= 1) {
        pos += __shfl_xor(pos, o);
        neg += __shfl_xor(neg, o);
        reg += __shfl_xor(reg, o);
    }
    if (lane == 0) {
        float x = pos - neg;
        float ls = (x >= 0.f) ? (-log1pf(expf(-x))) : (x - log1pf(expf(x)));
        atomicAdd(&scal[0], -ls);
        atomicAdd(&scal[1], reg * 0.5f);
    }
}

// ---------------- extract sampled rows from acc, l2-normalize -> bf16
__global__ void extract_norm_kernel(const float* __restrict__ acc, const int* __restrict__ uid,
                                    const int* __restrict__ iid, unsigned short* __restrict__ ue1b,
                                    unsigned short* __restrict__ ie1b, int B) {
    int gid = blockIdx.x * 256 + threadIdx.x;
    int t = gid >> 6;
    int lane = gid & 63;
    if (t >= 2 * B) return;
    bool user = (t < B);
    int r = user ? t : (t - B);
    size_t srow = user ? (size_t)uid[r] * D : (size_t)(USER_NUM + iid[r]) * D;
    float x = acc[srow + lane];
    float s = x * x;
    #pragma unroll
    for (int o = 32; o; o >>= 1) s += __shfl_xor(s, o);
    float y = x / fmaxf(sqrtf(s), 1e-12f);
    (user ? ue1b : ie1b)[(size_t)r * D + lane] = f2bf(y);
}

// ---------------- big SSL via MFMA, XCD-locality grid (see R6)
__global__ __launch_bounds__(256) void ssl_mfma_kernel(const unsigned short* __restrict__ Ab,
                                                       const unsigned short* __restrict__ Bb,
                                                       float* __restrict__ rowsum,
                                                       int M, int nc) {
    int bid = blockIdx.x;
    int xcd = bid & 7;
    int inner = bid >> 3;
    int rg = inner & (NRG - 1);
    int cgrp = inner >> 6;
    int colChunk = cgrp * 8 + xcd;
    if (colChunk >= nc) return;

    int wave = threadIdx.x >> 6;
    int lane = threadIdx.x & 63;
    int l15 = lane & 15;
    int lg  = lane >> 4;
    int rgbase = rg * 64;
    int chunkbase = colChunk * (128 * NCITER);

    bf16x8 afr[4][2];
    {
        const unsigned short* ab = Ab + (size_t)(rgbase + l15) * D + lg * 8;
        #pragma unroll
        for (int i = 0; i < 4; i++) {
            afr[i][0] = *(const bf16x8*)(ab + (size_t)i * 16 * D);
            afr[i][1] = *(const bf16x8*)(ab + (size_t)i * 16 * D + 32);
        }
    }

    float rowacc[4][4];
    #pragma unroll
    for (int i = 0; i < 4; i++)
        #pragma unroll
        for (int r = 0; r < 4; r++) rowacc[i][r] = 0.f;

    for (int it = 0; it < NCITER; it++) {
        int cb = chunkbase + it * 128 + wave * 32;
        bf16x8 bfr[2][2];
        bool val[2];
        #pragma unroll
        for (int cf = 0; cf < 2; cf++) {
            int col = cb + cf * 16 + l15;
            val[cf] = (col < M);
            int cc = val[cf] ? col : (M - 1);
            const unsigned short* bp = Bb + (size_t)cc * D + lg * 8;
            bfr[cf][0] = *(const bf16x8*)(bp);
            bfr[cf][1] = *(const bf16x8*)(bp + 32);
        }

        f32x4 acc[4][2];
        #pragma unroll
        for (int i = 0; i < 4; i++)
            #pragma unroll
            for (int cf = 0; cf < 2; cf++)
                acc[i][cf] = (f32x4){0.f, 0.f, 0.f, 0.f};

        #pragma unroll
        for (int i = 0; i < 4; i++) {
            #pragma unroll
            for (int cf = 0; cf < 2; cf++) {
                acc[i][cf] = __builtin_amdgcn_mfma_f32_16x16x32_bf16(afr[i][0], bfr[cf][0], acc[i][cf], 0, 0, 0);
                acc[i][cf] = __builtin_amdgcn_mfma_f32_16x16x32_bf16(afr[i][1], bfr[cf][1], acc[i][cf], 0, 0, 0);
            }
        }

        #pragma unroll
        for (int i = 0; i < 4; i++) {
            #pragma unroll
            for (int r = 0; r < 4; r++) {
                float e0 = val[0] ? __expf(TAU_INV * acc[i][0][r]) : 0.f;
                float e1 = val[1] ? __expf(TAU_INV * acc[i][1][r]) : 0.f;
                rowacc[i][r] += e0 + e1;
            }
        }
    }

    #pragma unroll
    for (int i = 0; i < 4; i++) {
        #pragma unroll
        for (int r = 0; r < 4; r++) {
            float s = rowacc[i][r];
            s += __shfl_xor(s, 1);
            s += __shfl_xor(s, 2);
            s += __shfl_xor(s, 4);
            s += __shfl_xor(s, 8);
            if (l15 == 0) atomicAdd(&rowsum[rgbase + i * 16 + lg * 4 + r], s);
        }
    }
}

// ---------------- SSL finalize
__global__ void ssl_fin_kernel(const unsigned short* __restrict__ ue1b,
                               const unsigned short* __restrict__ ie1b,
                               const float* __restrict__ A2, const int* __restrict__ uid,
                               const int* __restrict__ iid, const float* __restrict__ rsU,
                               const float* __restrict__ rsI, float* __restrict__ scal, int B) {
    int gid = blockIdx.x * 256 + threadIdx.x;
    int t = gid >> 6;
    int lane = gid & 63;
    if (t >= 2 * B) return;
    bool user = (t < B);
    int r = user ? t : (t - B);
    const unsigned short* a = (user ? ue1b : ie1b) + (size_t)r * D;
    size_t brow = user ? (size_t)uid[r] * D : (size_t)(USER_NUM + iid[r]) * D;
    float p = bf2f(a[lane]) * A2[brow + lane];
    #pragma unroll
    for (int o = 32; o; o >>= 1) p += __shfl_xor(p, o);
    if (lane == 0) {
        float contrib = logf((user ? rsU : rsI)[r]) - p * TAU_INV;
        atomicAdd(&scal[user ? 2 : 3], contrib);
    }
}

// ---------------- final scalar
__global__ void final_kernel(const float* __restrict__ scal, float* __restrict__ out, int B) {
    if (threadIdx.x == 0 && blockIdx.x == 0) {
        float invB = 1.0f / (float)B;
        float bpr_loss = scal[0] * invB + LMBD * scal[1] * invB;
        float ssl_loss = (scal[2] + scal[3]) * 0.1f;
        out[0] = bpr_loss + ssl_loss;
    }
}

extern "C" void kernel_launch(void* const* d_in, const int* in_sizes, int n_in,
                              void* d_out, int out_size, void* d_ws, size_t ws_size,
                              hipStream_t stream) {
    const float* user_emb = (const float*)d_in[0];
    const float* item_emb = (const float*)d_in[1];
    const int*   src  = (const int*)d_in[2];
    const int*   dst  = (const int*)d_in[3];
    const float* w    = (const float*)d_in[4];
    const int*   src1 = (const int*)d_in[5];
    const int*   dst1 = (const int*)d_in[6];
    const float* w1   = (const float*)d_in[7];
    const int*   src2 = (const int*)d_in[8];
    const int*   dst2 = (const int*)d_in[9];
    const float* w2   = (const float*)d_in[10];
    const int* user_id = (const int*)d_in[11];
    const int* item_id = (const int*)d_in[12];
    const int* neg_id  = (const int*)d_in[13];
    int E0 = in_sizes[2];
    int E1 = in_sizes[5];
    int E2 = in_sizes[8];
    int B  = in_sizes[11];
    int ET = E0 + E1 + E2;

    size_t nd = (size_t)NN * D;
    float* acc = (float*)d_ws;                       // fp32 NN*D
    unsigned short* hAb = (unsigned short*)(acc + nd);
    unsigned short* hBb = hAb + nd;
    unsigned short* ue1b = hBb + nd;
    unsigned short* ie1b = ue1b + (size_t)B * D;
    float* rsU  = (float*)(ie1b + (size_t)B * D);
    float* rsI  = rsU + B;
    float* scal = rsI + B;                 // 8 floats
    int* deg3    = (int*)(scal + 8);       // 3*NN
    int* rowptr3 = deg3 + T3;              // 3*NN + 1
    int* cursor3 = rowptr3 + T3 + 1;       // 3*NN
    int* bsum3   = cursor3 + T3;           // NBLK3 (<2048)
    int2* perm3  = (int2*)(((uintptr_t)(bsum3 + 2048) + 15) & ~(uintptr_t)15);  // ET entries
    unsigned short* bbuf = hAb;            // reuse after last propagation

    hipMemsetAsync(rsU, 0, (size_t)(2 * B + 8) * sizeof(float), stream);
    hipMemsetAsync(deg3, 0, (size_t)T3 * sizeof(int), stream);

    int gridElem = (NN * D + 255) / 256;
    int gridRows = (NN * 64 + 255) / 256;
    int gridE3 = (ET + 255) / 256;

    // ---- fused CSR build for all 3 graphs
    deg3_kernel<<<gridE3, 256, 0, stream>>>(dst, dst1, dst2, deg3, E0, E1, E2);
    scan_reduce_kernel<<<NBLK3, 256, 0, stream>>>(deg3, bsum3);
    scan_mid_kernel<<<1, 1024, 0, stream>>>(bsum3, rowptr3 + T3, NBLK3);
    scan_final_kernel<<<NBLK3, 256, 0, stream>>>(deg3, bsum3, rowptr3, cursor3);
    fill3_kernel<<<gridE3, 256, 0, stream>>>(src, dst, w, src1, dst1, w1, src2, dst2, w2,
                                             cursor3, perm3, E0, E1, E2);

    auto propagate = [&](int g, int layers) {
        const int* rp = rowptr3 + (size_t)g * NN;
        init_kernel<<<gridElem, 256, 0, stream>>>(user_emb, item_emb, hAb, acc);
        unsigned short* cur = hAb;
        unsigned short* nxt = hBb;
        for (int l = 0; l < layers; l++) {
            gather_norm_kernel<<<gridRows, 256, 0, stream>>>(cur, rp, perm3, nxt, acc);
            unsigned short* t = cur; cur = nxt; nxt = t;
        }
    };

    // main graph: 4 layers -> BPR
    propagate(0, 4);
    bpr_kernel<<<(B * 64) / 256, 256, 0, stream>>>(acc, user_id, item_id, neg_id, scal, B);

    // ssl graph 1: 3 layers -> bf16 normalized sampled rows
    propagate(1, 3);
    extract_norm_kernel<<<(2 * B * 64) / 256, 256, 0, stream>>>(acc, user_id, item_id, ue1b, ie1b, B);

    // ssl graph 2: 3 layers -> normalize acc in place + bf16 copy
    propagate(2, 3);
    norm_rows_bf_kernel<<<gridRows, 256, 0, stream>>>(acc, bbuf);

    // big SSL terms via MFMA (XCD-locality 1-D grid)
    {
        int ncU = (USER_NUM + 128 * NCITER - 1) / (128 * NCITER);
        int gu = 8 * NRG * ((ncU + 7) / 8);
        ssl_mfma_kernel<<<gu, 256, 0, stream>>>(ue1b, bbuf, rsU, USER_NUM, ncU);
        int ncI = (ITEM_NUM + 128 * NCITER - 1) / (128 * NCITER);
        int gi = 8 * NRG * ((ncI + 7) / 8);
        ssl_mfma_kernel<<<gi, 256, 0, stream>>>(ie1b, bbuf + (size_t)USER_NUM * D, rsI, ITEM_NUM, ncI);
    }

    ssl_fin_kernel<<<(2 * B * 64) / 256, 256, 0, stream>>>(ue1b, ie1b, acc, user_id, item_id,
                                                           rsU, rsI, scal, B);
    final_kernel<<<1, 64, 0, stream>>>(scal, (float*)d_out, B);
}